// Round 1
// baseline (263.729 us; speedup 1.0000x reference)
//
#include <hip/hip_runtime.h>
#include <cstdint>
#include <cstddef>

// ---------------------------------------------------------------------------
// HierarchicalQueryMatcher, N=2048, W=64, D=512.
// Decomposition:
//   LN1(x)@w1+b1 = rsig*(A[n,:]+B[w,:]) - rsig*mu*G + C
//     A = (q .* g1_top) @ w1_top        [2048,512]
//     B = (cm .* g1_bot) @ w1_bot       [64,512]
//     G = g1 @ w1 (full 1024-K),  C = beta1 @ w1 + b1
//     mu,var from per-row sums of q and cm.
//   h2 = gelu(h) @ w2 + b2 ; y = h2 + q[n]
//   out = 16 * dot(LN2(y), cmhat_w)/max(|LN2(y)|,eps)
//   Both epilogue quantities reduce to 6 streaming sums over columns:
//     S1=Σy S2=Σy² S3=Σy·g2² S4=Σy·g2β2 S5=Σy²·g2² S6=Σy·(g2·cmhat_w)
// Only real GEMM: [131072,512]@[512,512] bf16 MFMA, fused epilogue.
// ---------------------------------------------------------------------------

#define NQ 2048
#define NWC 64
#define DD 512
#define USE_GLOAD_LDS 1

typedef __attribute__((ext_vector_type(8))) short short8;
typedef __attribute__((ext_vector_type(8))) unsigned short ushort8;
typedef __attribute__((ext_vector_type(4))) float f32x4;

__device__ __forceinline__ unsigned short f2bf(float f) {
  unsigned u = __float_as_uint(f);
  u += 0x7fffu + ((u >> 16) & 1u);
  return (unsigned short)(u >> 16);
}

// tanh-form gelu; |err| vs exact erf-gelu < ~1e-3 (inside bf16 budget)
__device__ __forceinline__ float gelu_f(float h) {
  float h2 = h * h;
  float z2 = h * fmaf(h2, 0.0713548162726f, 1.59576912161f); // 2*0.79788456*(h+0.044715h^3)/h
  z2 = fminf(z2, 80.0f);
  float e = __expf(z2);
  return h * (e / (e + 1.0f));
}

__device__ __forceinline__ float wred(float v) {
#pragma unroll
  for (int m = 1; m < 64; m <<= 1) v += __shfl_xor(v, m, 64);
  return v;
}

// ---------------- small precompute kernels ----------------

__global__ void k_rowstats(const float* __restrict__ x, float* __restrict__ s,
                           float* __restrict__ ss) {
  int r = blockIdx.x;
  const float* row = x + (size_t)r * DD;
  float a = 0.f, b = 0.f;
  for (int c = threadIdx.x; c < DD; c += 256) {
    float v = row[c]; a += v; b = fmaf(v, v, b);
  }
  a = wred(a); b = wred(b);
  __shared__ float ra[4], rb[4];
  int wv = threadIdx.x >> 6;
  if ((threadIdx.x & 63) == 0) { ra[wv] = a; rb[wv] = b; }
  __syncthreads();
  if (threadIdx.x == 0) {
    s[r]  = ra[0] + ra[1] + ra[2] + ra[3];
    ss[r] = rb[0] + rb[1] + rb[2] + rb[3];
  }
}

__global__ void k_cm(const float* __restrict__ cm, const float* __restrict__ g2,
                     const float* __restrict__ b2v, float* __restrict__ cmhg,
                     float* __restrict__ c1, float* __restrict__ c2) {
  int w = blockIdx.x;
  const float* row = cm + (size_t)w * DD;
  float ss = 0.f;
  for (int c = threadIdx.x; c < DD; c += 256) { float v = row[c]; ss = fmaf(v, v, ss); }
  ss = wred(ss);
  __shared__ float rr[4]; __shared__ float s_inv;
  int wv = threadIdx.x >> 6;
  if ((threadIdx.x & 63) == 0) rr[wv] = ss;
  __syncthreads();
  if (threadIdx.x == 0) s_inv = 1.0f / fmaxf(sqrtf(rr[0]+rr[1]+rr[2]+rr[3]), 1e-12f);
  __syncthreads();
  float inv = s_inv;
  float a = 0.f, b = 0.f;
  for (int c = threadIdx.x; c < DD; c += 256) {
    float ch = row[c] * inv;
    float gv = g2[c];
    cmhg[(size_t)w * DD + c] = gv * ch;
    a = fmaf(gv, ch, a);
    b = fmaf(b2v[c], ch, b);
  }
  a = wred(a); b = wred(b);
  __shared__ float rc1[4], rc2[4];
  if ((threadIdx.x & 63) == 0) { rc1[wv] = a; rc2[wv] = b; }
  __syncthreads();
  if (threadIdx.x == 0) {
    c1[w] = rc1[0]+rc1[1]+rc1[2]+rc1[3];
    c2[w] = rc2[0]+rc2[1]+rc2[2]+rc2[3];
  }
}

__global__ void k_vec2(const float* __restrict__ g2, const float* __restrict__ b2v,
                       float* __restrict__ gg, float* __restrict__ gb,
                       float* __restrict__ scal) {
  int c = threadIdx.x; // 512
  float g = g2[c], b = b2v[c];
  gg[c] = g * g; gb[c] = g * b;
  float s0 = wred(g * g), s1 = wred(g * b), s2 = wred(b * b);
  __shared__ float r0[8], r1[8], r2[8];
  int wv = c >> 6;
  if ((c & 63) == 0) { r0[wv] = s0; r1[wv] = s1; r2[wv] = s2; }
  __syncthreads();
  if (c == 0) {
    float a=0,bb=0,cc=0;
    for (int i = 0; i < 8; ++i) { a+=r0[i]; bb+=r1[i]; cc+=r2[i]; }
    scal[0]=a; scal[1]=bb; scal[2]=cc;
  }
}

__global__ void k_gc(const float* __restrict__ g1, const float* __restrict__ be1,
                     const float* __restrict__ w1, const float* __restrict__ b1,
                     float* __restrict__ G, float* __restrict__ C) {
  int j = blockIdx.x * 256 + threadIdx.x; // 512 total
  float g = 0.f, c = 0.f;
#pragma unroll 4
  for (int k = 0; k < 2 * DD; ++k) {
    float wv = w1[(size_t)k * DD + j];
    g = fmaf(g1[k], wv, g);
    c = fmaf(be1[k], wv, c);
  }
  G[j] = g;
  C[j] = c + b1[j];
}

// pack W[K=512 rows starting at roff][512 cols] into MFMA fragment order:
// slot (ct,t,l) elem i  <-  W[roff + t*32 + (l>>4)*8 + i][ct*16 + (l&15)] (*scale)
__global__ void k_pack(const float* __restrict__ W, const float* __restrict__ scale,
                       int roff, unsigned short* __restrict__ out) {
  int tid = blockIdx.x * 512 + threadIdx.x; // 32768
  int l = tid & 63;
  int t = (tid >> 6) & 15;
  int ct = tid >> 10;
  int g = l >> 4;
  int col = (ct << 4) + (l & 15);
  ushort8 o;
#pragma unroll
  for (int i = 0; i < 8; ++i) {
    int k = t * 32 + g * 8 + i;
    float v = W[(size_t)(roff + k) * DD + col];
    if (scale) v *= scale[roff + k];
    o[i] = f2bf(v);
  }
  *(ushort8*)(out + (size_t)tid * 8) = o;
}

// OUT[M,512] = bf16(X[M,512]) @ packedW   (fp32 out). grid=(ncol/64, M/64), 256thr
__global__ __launch_bounds__(256) void k_gemm16(const float* __restrict__ X,
    const unsigned short* __restrict__ PW, float* __restrict__ Out) {
  int l = threadIdx.x & 63;
  int wv = threadIdx.x >> 6;
  int lr = l & 15, g = l >> 4;
  int r0 = blockIdx.y * 64 + wv * 16;
  int cb0 = blockIdx.x * 4;
  f32x4 acc[4] = {{0,0,0,0},{0,0,0,0},{0,0,0,0},{0,0,0,0}};
  const float* xrow = X + (size_t)(r0 + lr) * DD;
#pragma unroll
  for (int t = 0; t < 16; ++t) {
    int kb = t * 32 + g * 8;
    f32x4 x0 = *(const f32x4*)(xrow + kb);
    f32x4 x1 = *(const f32x4*)(xrow + kb + 4);
    short8 af;
#pragma unroll
    for (int i = 0; i < 4; ++i) { af[i] = (short)f2bf(x0[i]); af[4+i] = (short)f2bf(x1[i]); }
#pragma unroll
    for (int c = 0; c < 4; ++c) {
      short8 bf = *(const short8*)(PW + (size_t)(((cb0 + c) * 16 + t) * 64 + l) * 8);
      acc[c] = __builtin_amdgcn_mfma_f32_16x16x32_bf16(af, bf, acc[c], 0, 0, 0);
    }
  }
#pragma unroll
  for (int c = 0; c < 4; ++c)
#pragma unroll
    for (int r = 0; r < 4; ++r)
      Out[(size_t)(r0 + g * 4 + r) * DD + (cb0 + c) * 16 + lr] = acc[c][r];
}

// ---------------- fused main kernel ----------------

__device__ __forceinline__ void async16(const void* g, void* lds) {
#if USE_GLOAD_LDS
  __builtin_amdgcn_global_load_lds(
      (const __attribute__((address_space(1))) void*)(uintptr_t)g,
      (__attribute__((address_space(3))) void*)(unsigned int)(uintptr_t)lds,
      16, 0, 0);
#endif
}

__global__ __launch_bounds__(512, 2) void k_main(
    const float* __restrict__ Afull, const float* __restrict__ Bw,
    const float* __restrict__ G, const float* __restrict__ Cc,
    const float* __restrict__ q, const float* __restrict__ b2,
    const float* __restrict__ gg, const float* __restrict__ gb,
    const float* __restrict__ cmhg, const float* __restrict__ c1v,
    const float* __restrict__ c2v, const float* __restrict__ Sq,
    const float* __restrict__ SSq, const float* __restrict__ Sc,
    const float* __restrict__ SSc, const float* __restrict__ scal,
    const unsigned short* __restrict__ PW2, float* __restrict__ out) {

  __shared__ __align__(16) float sG[DD], sC[DD], sGG[DD], sGB[DD];
  __shared__ __align__(16) float sA[4][DD], sQB[4][DD];
  __shared__ __align__(16) unsigned short sW[2][16384];

  const int tid = threadIdx.x;
  const int wv = tid >> 6, l = tid & 63;
  const int g = l >> 4, lr = l & 15;
  const int n0 = blockIdx.x * 4;
  const int sub = wv >> 1;             // which n of the 4
  const int n = n0 + sub;
  const int whalf = wv & 1;            // w half: 0..31 or 32..63
  const int w0 = whalf * 32 + lr;      // pair-tile 0
  const int w1p = w0 + 16;             // pair-tile 1

  for (int c = tid; c < DD; c += 512) {
    sG[c] = G[c]; sC[c] = Cc[c]; sGG[c] = gg[c]; sGB[c] = gb[c];
  }
#pragma unroll
  for (int s = 0; s < 4; ++s) {
    sA[s][tid]  = Afull[(size_t)(n0 + s) * DD + tid];
    sQB[s][tid] = q[(size_t)(n0 + s) * DD + tid] + b2[tid];
  }
  __syncthreads();

  // LN1 scalars for this lane's two pairs
  float sqn = Sq[n], ssqn = SSq[n];
  float mu0 = (sqn + Sc[w0]) * (1.0f / 1024.0f);
  float rs0 = rsqrtf((ssqn + SSc[w0]) * (1.0f / 1024.0f) - mu0 * mu0 + 1e-5f);
  float mu1 = (sqn + Sc[w1p]) * (1.0f / 1024.0f);
  float rs1 = rsqrtf((ssqn + SSc[w1p]) * (1.0f / 1024.0f) - mu1 * mu1 + 1e-5f);

  // gelu fragments straight into MFMA B-operand layout (k = t*32 + 8g + i)
  short8 af0[16], af1[16];
  const float* bw0 = Bw + (size_t)w0 * DD;
  const float* bw1 = Bw + (size_t)w1p * DD;
#pragma unroll
  for (int t = 0; t < 16; ++t) {
    int kb = t * 32 + g * 8;
    f32x4 a0 = *(const f32x4*)&sA[sub][kb];
    f32x4 a1 = *(const f32x4*)&sA[sub][kb + 4];
    f32x4 g0 = *(const f32x4*)&sG[kb];
    f32x4 g1v = *(const f32x4*)&sG[kb + 4];
    f32x4 c0 = *(const f32x4*)&sC[kb];
    f32x4 c1f = *(const f32x4*)&sC[kb + 4];
    f32x4 b00 = *(const f32x4*)(bw0 + kb);
    f32x4 b01 = *(const f32x4*)(bw0 + kb + 4);
    f32x4 b10 = *(const f32x4*)(bw1 + kb);
    f32x4 b11 = *(const f32x4*)(bw1 + kb + 4);
    short8 f0, f1;
#pragma unroll
    for (int i = 0; i < 4; ++i) {
      float h;
      h = fmaf(rs0, a0[i] + b00[i] - mu0 * g0[i],  c0[i]);  f0[i]   = (short)f2bf(gelu_f(h));
      h = fmaf(rs0, a1[i] + b01[i] - mu0 * g1v[i], c1f[i]); f0[4+i] = (short)f2bf(gelu_f(h));
      h = fmaf(rs1, a0[i] + b10[i] - mu1 * g0[i],  c0[i]);  f1[i]   = (short)f2bf(gelu_f(h));
      h = fmaf(rs1, a1[i] + b11[i] - mu1 * g1v[i], c1f[i]); f1[4+i] = (short)f2bf(gelu_f(h));
    }
    af0[t] = f0; af1[t] = f1;
  }

  float S[2][6];
#pragma unroll
  for (int p = 0; p < 2; ++p)
#pragma unroll
    for (int i = 0; i < 6; ++i) S[p][i] = 0.f;

  // stage w2-chunk 0 (2 col-tiles = 32KB)
  {
    const unsigned short* src = PW2;
#pragma unroll
    for (int j = 0; j < 4; ++j) {
#if USE_GLOAD_LDS
      async16(src + (size_t)(j * 512 + tid) * 8, &sW[0][(j * 512 + wv * 64) * 8]);
#else
      *(ushort8*)&sW[0][(j*512+tid)*8] = *(const ushort8*)(src + (size_t)(j*512+tid)*8);
#endif
    }
  }

  for (int cc = 0; cc < 16; ++cc) {
    __syncthreads();                      // staged chunk cc ready; prev reads done
    if (cc < 15) {                        // prefetch next chunk
      const unsigned short* src = PW2 + (size_t)(cc + 1) * 16384;
      unsigned short* dst = sW[(cc + 1) & 1];
#pragma unroll
      for (int j = 0; j < 4; ++j) {
#if USE_GLOAD_LDS
        async16(src + (size_t)(j * 512 + tid) * 8, &dst[(j * 512 + wv * 64) * 8]);
#else
        *(ushort8*)&dst[(j*512+tid)*8] = *(const ushort8*)(src + (size_t)(j*512+tid)*8);
#endif
      }
    }
    const unsigned short* wbuf = sW[cc & 1];
    f32x4 acc00 = {0,0,0,0}, acc01 = {0,0,0,0}, acc10 = {0,0,0,0}, acc11 = {0,0,0,0};
#pragma unroll
    for (int t = 0; t < 16; ++t) {
      short8 bf0 = *(const short8*)(wbuf + (size_t)((t * 64 + l) * 8));
      short8 bf1 = *(const short8*)(wbuf + (size_t)(((16 + t) * 64 + l) * 8));
      acc00 = __builtin_amdgcn_mfma_f32_16x16x32_bf16(bf0, af0[t], acc00, 0, 0, 0);
      acc10 = __builtin_amdgcn_mfma_f32_16x16x32_bf16(bf0, af1[t], acc10, 0, 0, 0);
      acc01 = __builtin_amdgcn_mfma_f32_16x16x32_bf16(bf1, af0[t], acc01, 0, 0, 0);
      acc11 = __builtin_amdgcn_mfma_f32_16x16x32_bf16(bf1, af1[t], acc11, 0, 0, 0);
    }
    // streaming epilogue: lane holds cols cb..cb+3 (D rows = 4g+r) of pairs w0/w1p
#pragma unroll
    for (int ct = 0; ct < 2; ++ct) {
      int cb = cc * 32 + ct * 16 + g * 4;
      f32x4 qb4 = *(const f32x4*)&sQB[sub][cb];
      f32x4 gg4 = *(const f32x4*)&sGG[cb];
      f32x4 gb4 = *(const f32x4*)&sGB[cb];
      f32x4 ch0 = *(const f32x4*)(cmhg + (size_t)w0 * DD + cb);
      f32x4 ch1 = *(const f32x4*)(cmhg + (size_t)w1p * DD + cb);
      f32x4 a0v = ct ? acc01 : acc00;
      f32x4 a1v = ct ? acc11 : acc10;
#pragma unroll
      for (int r = 0; r < 4; ++r) {
        float y = a0v[r] + qb4[r];
        float y2 = y * y;
        S[0][0] += y; S[0][1] += y2;
        S[0][2] = fmaf(y,  gg4[r], S[0][2]);
        S[0][3] = fmaf(y,  gb4[r], S[0][3]);
        S[0][4] = fmaf(y2, gg4[r], S[0][4]);
        S[0][5] = fmaf(y,  ch0[r], S[0][5]);
        float z = a1v[r] + qb4[r];
        float z2 = z * z;
        S[1][0] += z; S[1][1] += z2;
        S[1][2] = fmaf(z,  gg4[r], S[1][2]);
        S[1][3] = fmaf(z,  gb4[r], S[1][3]);
        S[1][4] = fmaf(z2, gg4[r], S[1][4]);
        S[1][5] = fmaf(z,  ch1[r], S[1][5]);
      }
    }
  }

  // sum the 4 lane-groups (cols are split across g): xor over lane bits 4,5
#pragma unroll
  for (int p = 0; p < 2; ++p)
#pragma unroll
    for (int i = 0; i < 6; ++i) {
      float v = S[p][i];
      v += __shfl_xor(v, 16, 64);
      v += __shfl_xor(v, 32, 64);
      S[p][i] = v;
    }

  if (g == 0) {
    float sg2v = scal[0], sgbv = scal[1], sb2v = scal[2];
#pragma unroll
    for (int p = 0; p < 2; ++p) {
      int w = whalf * 32 + p * 16 + lr;
      float mu2 = S[p][0] * (1.0f / 512.0f);
      float var2 = S[p][1] * (1.0f / 512.0f) - mu2 * mu2;
      float rs2 = rsqrtf(var2 + 1e-5f);
      float n2 = rs2 * rs2 * (S[p][4] - 2.f * mu2 * S[p][2] + mu2 * mu2 * sg2v)
               + 2.f * rs2 * (S[p][3] - mu2 * sgbv) + sb2v;
      float nrm = sqrtf(fmaxf(n2, 0.f));
      float num = rs2 * (S[p][5] - mu2 * c1v[w]) + c2v[w];
      out[(size_t)n * NWC + w] = 16.0f * num / fmaxf(nrm, 1e-12f);
    }
  }
}

// ---------------- launch ----------------

extern "C" void kernel_launch(void* const* d_in, const int* in_sizes, int n_in,
                              void* d_out, int out_size, void* d_ws, size_t ws_size,
                              hipStream_t stream) {
  const float* q    = (const float*)d_in[0];
  const float* cm   = (const float*)d_in[1];
  const float* ln1w = (const float*)d_in[2];
  const float* ln1b = (const float*)d_in[3];
  const float* w1   = (const float*)d_in[4];
  const float* b1   = (const float*)d_in[5];
  const float* w2   = (const float*)d_in[6];
  const float* b2   = (const float*)d_in[7];
  const float* ln2w = (const float*)d_in[8];
  const float* ln2b = (const float*)d_in[9];
  float* out = (float*)d_out;

  char* p = (char*)d_ws;
  auto alloc = [&](size_t bytes) { char* r = p; p += (bytes + 255) & ~(size_t)255; return r; };
  float* A    = (float*)alloc((size_t)NQ * DD * 4);
  float* Bw   = (float*)alloc((size_t)NWC * DD * 4);
  float* G    = (float*)alloc(DD * 4);
  float* C    = (float*)alloc(DD * 4);
  float* Sq   = (float*)alloc(NQ * 4);
  float* SSq  = (float*)alloc(NQ * 4);
  float* Sc   = (float*)alloc(NWC * 4);
  float* SSc  = (float*)alloc(NWC * 4);
  float* cmhg = (float*)alloc((size_t)NWC * DD * 4);
  float* c1   = (float*)alloc(NWC * 4);
  float* c2   = (float*)alloc(NWC * 4);
  float* gg   = (float*)alloc(DD * 4);
  float* gb   = (float*)alloc(DD * 4);
  float* scal = (float*)alloc(256);
  unsigned short* PW1T = (unsigned short*)alloc((size_t)DD * DD * 2);
  unsigned short* PW1B = (unsigned short*)alloc((size_t)DD * DD * 2);
  unsigned short* PW2  = (unsigned short*)alloc((size_t)DD * DD * 2);

  k_rowstats<<<NQ, 256, 0, stream>>>(q, Sq, SSq);
  k_rowstats<<<NWC, 256, 0, stream>>>(cm, Sc, SSc);
  k_cm<<<NWC, 256, 0, stream>>>(cm, ln2w, ln2b, cmhg, c1, c2);
  k_vec2<<<1, 512, 0, stream>>>(ln2w, ln2b, gg, gb, scal);
  k_gc<<<2, 256, 0, stream>>>(ln1w, ln1b, w1, b1, G, C);
  k_pack<<<64, 512, 0, stream>>>(w1, ln1w, 0, PW1T);
  k_pack<<<64, 512, 0, stream>>>(w1, ln1w, 512, PW1B);
  k_pack<<<64, 512, 0, stream>>>(w2, (const float*)nullptr, 0, PW2);
  k_gemm16<<<dim3(8, 32), 256, 0, stream>>>(q, PW1T, A);
  k_gemm16<<<dim3(8, 1), 256, 0, stream>>>(cm, PW1B, Bw);
  k_main<<<512, 512, 0, stream>>>(A, Bw, G, C, q, b2, gg, gb, cmhg, c1, c2,
                                  Sq, SSq, Sc, SSc, scal, PW2, out);
}